// Round 1
// baseline (666.813 us; speedup 1.0000x reference)
//
#include <hip/hip_runtime.h>
#include <math.h>

#define FDIM 64

// ---- degree / norm precompute -------------------------------------------

__global__ __launch_bounds__(256) void k_init_deg(float* __restrict__ deg, int N) {
    int i = blockIdx.x * 256 + threadIdx.x;
    if (i < N) deg[i] = 1.0f;  // self-loop contributes 1
}

__global__ __launch_bounds__(256) void k_count_deg(const int* __restrict__ dst,
                                                   float* __restrict__ deg, int E) {
    int e = blockIdx.x * 256 + threadIdx.x;
    if (e < E) atomicAdd(&deg[dst[e]], 1.0f);
}

__global__ __launch_bounds__(256) void k_dinv(float* __restrict__ deg, int N) {
    int i = blockIdx.x * 256 + threadIdx.x;
    if (i < N) deg[i] = rsqrtf(deg[i]);  // deg >= 1 always (self-loop)
}

__global__ __launch_bounds__(256) void k_norm(const int* __restrict__ src,
                                              const int* __restrict__ dst,
                                              const float* __restrict__ dinv,
                                              float* __restrict__ norm, int E) {
    int e = blockIdx.x * 256 + threadIdx.x;
    if (e < E) norm[e] = dinv[src[e]] * dinv[dst[e]];
}

// ---- propagation hop ----------------------------------------------------

// y[i][:] = dinv[i]^2 * x[i][:]   (self-loop term; also initializes y)
__global__ __launch_bounds__(256) void k_self_init(const float* __restrict__ x,
                                                   const float* __restrict__ dinv,
                                                   float* __restrict__ y, int N) {
    int t = blockIdx.x * 256 + threadIdx.x;
    int i = t >> 6;
    if (i < N) {
        float d = dinv[i];
        y[t] = d * d * x[t];
    }
}

// y[dst][f] += norm[e] * x[src][f]; one edge per wave, lane = feature
__global__ __launch_bounds__(256) void k_scatter(const int* __restrict__ src,
                                                 const int* __restrict__ dst,
                                                 const float* __restrict__ norm,
                                                 const float* __restrict__ xin,
                                                 float* __restrict__ y, int E) {
    int t = blockIdx.x * 256 + threadIdx.x;
    int e = t >> 6;
    int f = t & 63;
    if (e < E) {
        int s = src[e];
        int d = dst[e];
        float v = norm[e] * xin[s * FDIM + f];
        atomicAdd(&y[d * FDIM + f], v);
    }
}

// ---- projection + log_softmax -------------------------------------------
// one wave per node; lane c (< C) computes logit_c; shuffle-reduce softmax

__global__ __launch_bounds__(256) void k_mm_lsm(const float* __restrict__ x,
                                                const float* __restrict__ W,
                                                const float* __restrict__ b,
                                                float* __restrict__ out,
                                                int N, int C) {
    __shared__ float Wl[64 * 65];   // padded: kills stride-64 bank conflict
    __shared__ float xl[4][FDIM];

    // cooperative load of W [C][FDIM] into padded LDS
    for (int i = threadIdx.x; i < C * FDIM; i += 256) {
        int c = i >> 6, f = i & 63;
        Wl[c * 65 + f] = W[i];
    }

    int wave = threadIdx.x >> 6;
    int lane = threadIdx.x & 63;
    int node = blockIdx.x * 4 + wave;

    float xv = 0.0f;
    if (node < N) xv = x[node * FDIM + lane];
    xl[wave][lane] = xv;
    __syncthreads();

    float logit = -INFINITY;
    if (lane < C) {
        const float* wr = &Wl[lane * 65];
        const float* xr = xl[wave];
        float acc = 0.0f;
#pragma unroll
        for (int f = 0; f < FDIM; ++f) acc = fmaf(xr[f], wr[f], acc);
        logit = acc + b[lane];
    }

    // wave-wide max
    float m = logit;
#pragma unroll
    for (int o = 32; o > 0; o >>= 1) m = fmaxf(m, __shfl_xor(m, o));
    // wave-wide sum of exp
    float ev = (lane < C) ? expf(logit - m) : 0.0f;
    float s = ev;
#pragma unroll
    for (int o = 32; o > 0; o >>= 1) s += __shfl_xor(s, o);

    if (node < N && lane < C) out[node * C + lane] = logit - m - logf(s);
}

// ---- launch --------------------------------------------------------------

extern "C" void kernel_launch(void* const* d_in, const int* in_sizes, int n_in,
                              void* d_out, int out_size, void* d_ws, size_t ws_size,
                              hipStream_t stream) {
    const float* x  = (const float*)d_in[0];
    const int*   ei = (const int*)d_in[1];
    const float* W  = (const float*)d_in[2];
    const float* b  = (const float*)d_in[3];
    float* out = (float*)d_out;

    const int C = in_sizes[3];              // 40
    const int F = in_sizes[2] / C;          // 64
    const int N = in_sizes[0] / F;          // 100000
    const int E = in_sizes[1] / 2;          // 1200000
    (void)F; // layout hardcoded to FDIM=64

    const int* src = ei;
    const int* dst = ei + E;

    float* ws   = (float*)d_ws;
    float* dinv = ws;                        // N
    float* norm = dinv + N;                  // E
    float* y1   = norm + E;                  // N*FDIM
    float* y2   = y1 + (size_t)N * FDIM;     // N*FDIM

    const int B = 256;
    // degrees -> dinv -> per-edge norm
    k_init_deg <<<(N + B - 1) / B, B, 0, stream>>>(dinv, N);
    k_count_deg<<<(E + B - 1) / B, B, 0, stream>>>(dst, dinv, E);
    k_dinv     <<<(N + B - 1) / B, B, 0, stream>>>(dinv, N);
    k_norm     <<<(E + B - 1) / B, B, 0, stream>>>(src, dst, dinv, norm, E);

    const int nodeT = N * FDIM;              // 6.4M
    const int edgeT = E * FDIM;              // 76.8M

    // hop 1: x -> y1
    k_self_init<<<(nodeT + B - 1) / B, B, 0, stream>>>(x, dinv, y1, N);
    k_scatter  <<<(edgeT + B - 1) / B, B, 0, stream>>>(src, dst, norm, x, y1, E);
    // hop 2: y1 -> y2
    k_self_init<<<(nodeT + B - 1) / B, B, 0, stream>>>(y1, dinv, y2, N);
    k_scatter  <<<(edgeT + B - 1) / B, B, 0, stream>>>(src, dst, norm, y1, y2, E);

    // projection + log_softmax
    k_mm_lsm<<<(N + 3) / 4, B, 0, stream>>>(y2, W, b, out, N, C);
}

// Round 2
// 306.889 us; speedup vs baseline: 2.1728x; 2.1728x over previous
//
#include <hip/hip_runtime.h>
#include <math.h>

#define FDIM 64

// ---------------- degree histogram ----------------

__global__ __launch_bounds__(256) void k_zero(int* __restrict__ p, int n) {
    int i = blockIdx.x * 256 + threadIdx.x;
    if (i < n) p[i] = 0;
}

__global__ __launch_bounds__(256) void k_count(const int* __restrict__ dst,
                                               int* __restrict__ cnt, int E) {
    int e = blockIdx.x * 256 + threadIdx.x;
    if (e < E) atomicAdd(&cnt[dst[e]], 1);
}

__global__ __launch_bounds__(256) void k_dinv(const int* __restrict__ cnt,
                                              float* __restrict__ dinv, int N) {
    int i = blockIdx.x * 256 + threadIdx.x;
    if (i < N) dinv[i] = rsqrtf((float)(cnt[i] + 1));  // +1 self-loop
}

// ---------------- exclusive scan (1024 items / block) ----------------

__global__ __launch_bounds__(256) void k_scan1(const int* __restrict__ cnt,
                                               int* __restrict__ row_ptr,
                                               int* __restrict__ blkSums, int N) {
    __shared__ int lds[256];
    int tid = threadIdx.x;
    int base = blockIdx.x * 1024 + tid * 4;
    int v0 = (base + 0) < N ? cnt[base + 0] : 0;
    int v1 = (base + 1) < N ? cnt[base + 1] : 0;
    int v2 = (base + 2) < N ? cnt[base + 2] : 0;
    int v3 = (base + 3) < N ? cnt[base + 3] : 0;
    int tsum = v0 + v1 + v2 + v3;
    lds[tid] = tsum;
    __syncthreads();
    int val = tsum;
#pragma unroll
    for (int off = 1; off < 256; off <<= 1) {
        int other = (tid >= off) ? lds[tid - off] : 0;
        __syncthreads();
        val += other;
        lds[tid] = val;
        __syncthreads();
    }
    int excl = val - tsum;  // exclusive prefix within block
    if (base + 0 < N) row_ptr[base + 0] = excl;
    if (base + 1 < N) row_ptr[base + 1] = excl + v0;
    if (base + 2 < N) row_ptr[base + 2] = excl + v0 + v1;
    if (base + 3 < N) row_ptr[base + 3] = excl + v0 + v1 + v2;
    if (tid == 255) blkSums[blockIdx.x] = val;  // block total
}

__global__ __launch_bounds__(128) void k_scan2(int* __restrict__ blkSums, int nb) {
    __shared__ int lds[128];
    int tid = threadIdx.x;
    int v = (tid < nb) ? blkSums[tid] : 0;
    lds[tid] = v;
    __syncthreads();
    int val = v;
#pragma unroll
    for (int off = 1; off < 128; off <<= 1) {
        int other = (tid >= off) ? lds[tid - off] : 0;
        __syncthreads();
        val += other;
        lds[tid] = val;
        __syncthreads();
    }
    if (tid < nb) blkSums[tid] = val - v;  // exclusive
}

__global__ __launch_bounds__(256) void k_scan3(int* __restrict__ row_ptr,
                                               int* __restrict__ cursor,
                                               const int* __restrict__ blkSums,
                                               int N, int E) {
    int i = blockIdx.x * 256 + threadIdx.x;
    if (i < N) {
        int v = row_ptr[i] + blkSums[i >> 10];
        row_ptr[i] = v;
        cursor[i] = v;
    }
    if (i == N) row_ptr[N] = E;
}

// ---------------- CSR fill ----------------

__global__ __launch_bounds__(256) void k_fill(const int* __restrict__ src,
                                              const int* __restrict__ dst,
                                              const float* __restrict__ dinv,
                                              int* __restrict__ cursor,
                                              int* __restrict__ csr_src,
                                              float* __restrict__ csr_w, int E) {
    int e = blockIdx.x * 256 + threadIdx.x;
    if (e < E) {
        int s = src[e], d = dst[e];
        int pos = atomicAdd(&cursor[d], 1);
        csr_src[pos] = s;
        csr_w[pos] = dinv[s] * dinv[d];
    }
}

// ---------------- hop 1: gather (wave per node, lane = feature) ----------------

__global__ __launch_bounds__(256) void k_gather(const int* __restrict__ row_ptr,
                                                const int* __restrict__ csr_src,
                                                const float* __restrict__ csr_w,
                                                const float* __restrict__ dinv,
                                                const float* __restrict__ xin,
                                                float* __restrict__ y, int N) {
    int wid = (blockIdx.x << 2) | (threadIdx.x >> 6);
    int lane = threadIdx.x & 63;
    if (wid >= N) return;
    int beg = row_ptr[wid], end = row_ptr[wid + 1];
    float d = dinv[wid];
    float acc = d * d * xin[(size_t)wid * FDIM + lane];
    int e = beg;
    for (; e + 4 <= end; e += 4) {
        int s0 = csr_src[e + 0], s1 = csr_src[e + 1];
        int s2 = csr_src[e + 2], s3 = csr_src[e + 3];
        float w0 = csr_w[e + 0], w1 = csr_w[e + 1];
        float w2 = csr_w[e + 2], w3 = csr_w[e + 3];
        float v0 = xin[(size_t)s0 * FDIM + lane];
        float v1 = xin[(size_t)s1 * FDIM + lane];
        float v2 = xin[(size_t)s2 * FDIM + lane];
        float v3 = xin[(size_t)s3 * FDIM + lane];
        acc = fmaf(w0, v0, acc);
        acc = fmaf(w1, v1, acc);
        acc = fmaf(w2, v2, acc);
        acc = fmaf(w3, v3, acc);
    }
    for (; e < end; ++e)
        acc = fmaf(csr_w[e], xin[(size_t)csr_src[e] * FDIM + lane], acc);
    y[(size_t)wid * FDIM + lane] = acc;
}

// ---------------- hop 2 fused with projection + log_softmax ----------------

__global__ __launch_bounds__(256) void k_h2_mm_lsm(const int* __restrict__ row_ptr,
                                                   const int* __restrict__ csr_src,
                                                   const float* __restrict__ csr_w,
                                                   const float* __restrict__ dinv,
                                                   const float* __restrict__ xin,
                                                   const float* __restrict__ W,
                                                   const float* __restrict__ b,
                                                   float* __restrict__ out,
                                                   int N, int C) {
    __shared__ float Wl[40 * 65];
    __shared__ float bl[40];
    __shared__ float xl[4][FDIM];

    for (int i = threadIdx.x; i < C * FDIM; i += 256) {
        int c = i >> 6, f = i & 63;
        Wl[c * 65 + f] = W[i];
    }
    if (threadIdx.x < C) bl[threadIdx.x] = b[threadIdx.x];
    __syncthreads();

    int wave = threadIdx.x >> 6;
    int lane = threadIdx.x & 63;
    int node = blockIdx.x * 4 + wave;

    float acc = 0.0f;
    if (node < N) {
        int beg = row_ptr[node], end = row_ptr[node + 1];
        float d = dinv[node];
        acc = d * d * xin[(size_t)node * FDIM + lane];
        int e = beg;
        for (; e + 4 <= end; e += 4) {
            int s0 = csr_src[e + 0], s1 = csr_src[e + 1];
            int s2 = csr_src[e + 2], s3 = csr_src[e + 3];
            float w0 = csr_w[e + 0], w1 = csr_w[e + 1];
            float w2 = csr_w[e + 2], w3 = csr_w[e + 3];
            float v0 = xin[(size_t)s0 * FDIM + lane];
            float v1 = xin[(size_t)s1 * FDIM + lane];
            float v2 = xin[(size_t)s2 * FDIM + lane];
            float v3 = xin[(size_t)s3 * FDIM + lane];
            acc = fmaf(w0, v0, acc);
            acc = fmaf(w1, v1, acc);
            acc = fmaf(w2, v2, acc);
            acc = fmaf(w3, v3, acc);
        }
        for (; e < end; ++e)
            acc = fmaf(csr_w[e], xin[(size_t)csr_src[e] * FDIM + lane], acc);
    }
    xl[wave][lane] = acc;  // wave-local: no cross-wave sharing, no barrier needed

    float logit = -INFINITY;
    if (lane < C) {
        const float* wr = &Wl[lane * 65];
        const float* xr = xl[wave];
        float a = 0.0f;
#pragma unroll
        for (int f = 0; f < FDIM; ++f) a = fmaf(xr[f], wr[f], a);
        logit = a + bl[lane];
    }

    float m = logit;
#pragma unroll
    for (int o = 32; o > 0; o >>= 1) m = fmaxf(m, __shfl_xor(m, o));
    float ev = (lane < C) ? expf(logit - m) : 0.0f;
    float s = ev;
#pragma unroll
    for (int o = 32; o > 0; o >>= 1) s += __shfl_xor(s, o);

    if (node < N && lane < C) out[(size_t)node * C + lane] = logit - m - logf(s);
}

// ---------------- launch ----------------

extern "C" void kernel_launch(void* const* d_in, const int* in_sizes, int n_in,
                              void* d_out, int out_size, void* d_ws, size_t ws_size,
                              hipStream_t stream) {
    const float* x  = (const float*)d_in[0];
    const int*   ei = (const int*)d_in[1];
    const float* W  = (const float*)d_in[2];
    const float* b  = (const float*)d_in[3];
    float* out = (float*)d_out;

    const int C = in_sizes[3];              // 40
    const int F = in_sizes[2] / C;          // 64
    const int N = in_sizes[0] / F;          // 100000
    const int E = in_sizes[1] / 2;          // 1200000
    (void)F;

    const int* src = ei;
    const int* dst = ei + E;

    // ws layout (all 4-byte elems)
    char* w8 = (char*)d_ws;
    int*   cnt     = (int*)w8;                    w8 += (size_t)N * 4;
    int*   row_ptr = (int*)w8;                    w8 += (size_t)(N + 1) * 4;
    int*   cursor  = (int*)w8;                    w8 += (size_t)N * 4;
    int*   blkSums = (int*)w8;                    w8 += 128 * 4;
    float* dinv    = (float*)w8;                  w8 += (size_t)N * 4;
    int*   csr_src = (int*)w8;                    w8 += (size_t)E * 4;
    float* csr_w   = (float*)w8;                  w8 += (size_t)E * 4;
    float* y1      = (float*)w8;                  // N*FDIM

    const int B = 256;
    const int nb = (N + 1023) / 1024;  // scan blocks (<=128)

    k_zero <<<(N + B - 1) / B, B, 0, stream>>>(cnt, N);
    k_count<<<(E + B - 1) / B, B, 0, stream>>>(dst, cnt, E);
    k_dinv <<<(N + B - 1) / B, B, 0, stream>>>(cnt, dinv, N);

    k_scan1<<<nb, B, 0, stream>>>(cnt, row_ptr, blkSums, N);
    k_scan2<<<1, 128, 0, stream>>>(blkSums, nb);
    k_scan3<<<(N + 1 + B - 1) / B, B, 0, stream>>>(row_ptr, cursor, blkSums, N, E);

    k_fill <<<(E + B - 1) / B, B, 0, stream>>>(src, dst, dinv, cursor,
                                               csr_src, csr_w, E);

    k_gather<<<(N + 3) / 4, B, 0, stream>>>(row_ptr, csr_src, csr_w, dinv, x, y1, N);

    k_h2_mm_lsm<<<(N + 3) / 4, B, 0, stream>>>(row_ptr, csr_src, csr_w, dinv, y1,
                                               W, b, out, N, C);
}

// Round 3
// 278.560 us; speedup vs baseline: 2.3938x; 1.1017x over previous
//
#include <hip/hip_runtime.h>
#include <math.h>

#define FDIM 64   // input feature dim
#define CPAD 64   // padded class dim (40 valid), bf16 -> 128B rows

// ---------------- helpers ----------------

__device__ inline unsigned short f2bf(float f) {
    unsigned int u = __float_as_uint(f);
    unsigned int r = (u + 0x7fffu + ((u >> 16) & 1u)) >> 16;  // RNE
    return (unsigned short)r;
}
__device__ inline float bf_lo(unsigned int v) { return __uint_as_float(v << 16); }
__device__ inline float bf_hi(unsigned int v) { return __uint_as_float(v & 0xffff0000u); }
__device__ inline unsigned int bfpack(float a, float b) {
    return (unsigned int)f2bf(a) | ((unsigned int)f2bf(b) << 16);
}

// ---------------- degree histogram ----------------

__global__ __launch_bounds__(256) void k_zero(int* __restrict__ p, int n) {
    int i = blockIdx.x * 256 + threadIdx.x;
    if (i < n) p[i] = 0;
}

__global__ __launch_bounds__(256) void k_count(const int* __restrict__ dst,
                                               int* __restrict__ cnt, int E) {
    int e = blockIdx.x * 256 + threadIdx.x;
    if (e < E) atomicAdd(&cnt[dst[e]], 1);
}

__global__ __launch_bounds__(256) void k_dinv(const int* __restrict__ cnt,
                                              float* __restrict__ dinv, int N) {
    int i = blockIdx.x * 256 + threadIdx.x;
    if (i < N) dinv[i] = rsqrtf((float)(cnt[i] + 1));  // +1 self-loop
}

// ---------------- exclusive scan over (cnt[i]+1), 1024 items/block ----------

__global__ __launch_bounds__(256) void k_scan1(const int* __restrict__ cnt,
                                               int* __restrict__ row_ptr,
                                               int* __restrict__ blkSums, int N) {
    __shared__ int lds[256];
    int tid = threadIdx.x;
    int base = blockIdx.x * 1024 + tid * 4;
    int v0 = (base + 0) < N ? cnt[base + 0] + 1 : 0;   // +1: self entry
    int v1 = (base + 1) < N ? cnt[base + 1] + 1 : 0;
    int v2 = (base + 2) < N ? cnt[base + 2] + 1 : 0;
    int v3 = (base + 3) < N ? cnt[base + 3] + 1 : 0;
    int tsum = v0 + v1 + v2 + v3;
    lds[tid] = tsum;
    __syncthreads();
    int val = tsum;
#pragma unroll
    for (int off = 1; off < 256; off <<= 1) {
        int other = (tid >= off) ? lds[tid - off] : 0;
        __syncthreads();
        val += other;
        lds[tid] = val;
        __syncthreads();
    }
    int excl = val - tsum;
    if (base + 0 < N) row_ptr[base + 0] = excl;
    if (base + 1 < N) row_ptr[base + 1] = excl + v0;
    if (base + 2 < N) row_ptr[base + 2] = excl + v0 + v1;
    if (base + 3 < N) row_ptr[base + 3] = excl + v0 + v1 + v2;
    if (tid == 255) blkSums[blockIdx.x] = val;
}

__global__ __launch_bounds__(128) void k_scan2(int* __restrict__ blkSums, int nb) {
    __shared__ int lds[128];
    int tid = threadIdx.x;
    int v = (tid < nb) ? blkSums[tid] : 0;
    lds[tid] = v;
    __syncthreads();
    int val = v;
#pragma unroll
    for (int off = 1; off < 128; off <<= 1) {
        int other = (tid >= off) ? lds[tid - off] : 0;
        __syncthreads();
        val += other;
        lds[tid] = val;
        __syncthreads();
    }
    if (tid < nb) blkSums[tid] = val - v;
}

__global__ __launch_bounds__(256) void k_scan3(int* __restrict__ row_ptr,
                                               int* __restrict__ cursor,
                                               const int* __restrict__ blkSums,
                                               int N, int total) {
    int i = blockIdx.x * 256 + threadIdx.x;
    if (i < N) {
        int v = row_ptr[i] + blkSums[i >> 10];
        row_ptr[i] = v;
        cursor[i] = v;
    }
    if (i == N) row_ptr[N] = total;
}

// ---------------- CSR fill (edges + self entries) ----------------

__global__ __launch_bounds__(256) void k_fill(const int* __restrict__ src,
                                              const int* __restrict__ dst,
                                              const float* __restrict__ dinv,
                                              int* __restrict__ cursor,
                                              int* __restrict__ csr_src,
                                              float* __restrict__ csr_w,
                                              int E, int N) {
    int e = blockIdx.x * 256 + threadIdx.x;
    if (e < E) {
        int s = src[e], d = dst[e];
        int pos = atomicAdd(&cursor[d], 1);
        csr_src[pos] = s;
        csr_w[pos] = dinv[s] * dinv[d];
    } else if (e < E + N) {
        int i = e - E;                         // self entry
        int pos = atomicAdd(&cursor[i], 1);
        float d = dinv[i];
        csr_src[pos] = i;
        csr_w[pos] = d * d;
    }
}

// ---------------- projection: p[n][c] = dot(x[n], W[c]), bf16-packed --------

__global__ __launch_bounds__(256) void k_proj(const float* __restrict__ x,
                                              const float* __restrict__ W,
                                              unsigned short* __restrict__ p16,
                                              int N, int C) {
    __shared__ float Wl[40 * 65];
    __shared__ float xl[4][FDIM];

    for (int i = threadIdx.x; i < C * FDIM; i += 256) {
        int c = i >> 6, f = i & 63;
        Wl[c * 65 + f] = W[i];
    }
    int wave = threadIdx.x >> 6;
    int lane = threadIdx.x & 63;
    int node = blockIdx.x * 4 + wave;

    float xv = 0.0f;
    if (node < N) xv = x[(size_t)node * FDIM + lane];
    xl[wave][lane] = xv;
    __syncthreads();

    unsigned short r = 0;
    if (lane < C) {
        const float* wr = &Wl[lane * 65];
        const float* xr = xl[wave];
        float a = 0.0f;
#pragma unroll
        for (int f = 0; f < FDIM; ++f) a = fmaf(xr[f], wr[f], a);
        r = f2bf(a);
    }
    if (node < N) p16[(size_t)node * CPAD + lane] = r;  // pad lanes write 0
}

// ---------------- hop 1: gather in class space (bf16 rows, 128B/line) ------
// wave per node; lanes 0-31 take even CSR entries, 32-63 odd; lane j = class
// pair (2j, 2j+1) as one uint.

__global__ __launch_bounds__(256) void k_hop1(const int* __restrict__ row_ptr,
                                              const int* __restrict__ csr_src,
                                              const float* __restrict__ csr_w,
                                              const unsigned int* __restrict__ pin,
                                              unsigned int* __restrict__ yout,
                                              int N) {
    int wid = (blockIdx.x << 2) | (threadIdx.x >> 6);
    int lane = threadIdx.x & 63;
    int j = lane & 31;
    if (wid >= N) return;
    int beg = row_ptr[wid], end = row_ptr[wid + 1];

    float a0 = 0.0f, a1 = 0.0f;
    int e = beg + (lane >> 5);
    for (; e + 2 < end; e += 4) {
        int s0 = csr_src[e], s1 = csr_src[e + 2];
        float w0 = csr_w[e], w1 = csr_w[e + 2];
        unsigned int v0 = pin[s0 * 32 + j];
        unsigned int v1 = pin[s1 * 32 + j];
        a0 = fmaf(w0, bf_lo(v0), a0); a1 = fmaf(w0, bf_hi(v0), a1);
        a0 = fmaf(w1, bf_lo(v1), a0); a1 = fmaf(w1, bf_hi(v1), a1);
    }
    if (e < end) {
        int s = csr_src[e];
        float w = csr_w[e];
        unsigned int v = pin[s * 32 + j];
        a0 = fmaf(w, bf_lo(v), a0); a1 = fmaf(w, bf_hi(v), a1);
    }
    a0 += __shfl_xor(a0, 32);
    a1 += __shfl_xor(a1, 32);
    if (lane < 32) yout[wid * 32 + j] = bfpack(a0, a1);
}

// ---------------- hop 2 fused with bias + log_softmax ----------------------

__global__ __launch_bounds__(256) void k_hop2_lsm(const int* __restrict__ row_ptr,
                                                  const int* __restrict__ csr_src,
                                                  const float* __restrict__ csr_w,
                                                  const unsigned int* __restrict__ pin,
                                                  const float* __restrict__ b,
                                                  float* __restrict__ out,
                                                  int N, int C) {
    int wid = (blockIdx.x << 2) | (threadIdx.x >> 6);
    int lane = threadIdx.x & 63;
    int j = lane & 31;
    if (wid >= N) return;
    int beg = row_ptr[wid], end = row_ptr[wid + 1];

    float a0 = 0.0f, a1 = 0.0f;
    int e = beg + (lane >> 5);
    for (; e + 2 < end; e += 4) {
        int s0 = csr_src[e], s1 = csr_src[e + 2];
        float w0 = csr_w[e], w1 = csr_w[e + 2];
        unsigned int v0 = pin[s0 * 32 + j];
        unsigned int v1 = pin[s1 * 32 + j];
        a0 = fmaf(w0, bf_lo(v0), a0); a1 = fmaf(w0, bf_hi(v0), a1);
        a0 = fmaf(w1, bf_lo(v1), a0); a1 = fmaf(w1, bf_hi(v1), a1);
    }
    if (e < end) {
        int s = csr_src[e];
        float w = csr_w[e];
        unsigned int v = pin[s * 32 + j];
        a0 = fmaf(w, bf_lo(v), a0); a1 = fmaf(w, bf_hi(v), a1);
    }
    a0 += __shfl_xor(a0, 32);
    a1 += __shfl_xor(a1, 32);

    int c0 = 2 * j;
    bool valid = (c0 < C);
    float l0 = -INFINITY, l1 = -INFINITY;
    if (valid) {
        l0 = a0 + b[c0];
        l1 = a1 + b[c0 + 1];
    }
    float m = fmaxf(l0, l1);
#pragma unroll
    for (int o = 16; o > 0; o >>= 1) m = fmaxf(m, __shfl_xor(m, o));
    float s = valid ? (expf(l0 - m) + expf(l1 - m)) : 0.0f;
#pragma unroll
    for (int o = 16; o > 0; o >>= 1) s += __shfl_xor(s, o);
    float ls = logf(s);

    if (lane < 32 && valid) {
        float2 r = make_float2(l0 - m - ls, l1 - m - ls);
        *(float2*)&out[(size_t)wid * C + c0] = r;
    }
}

// ---------------- launch ----------------

extern "C" void kernel_launch(void* const* d_in, const int* in_sizes, int n_in,
                              void* d_out, int out_size, void* d_ws, size_t ws_size,
                              hipStream_t stream) {
    const float* x  = (const float*)d_in[0];
    const int*   ei = (const int*)d_in[1];
    const float* W  = (const float*)d_in[2];
    const float* b  = (const float*)d_in[3];
    float* out = (float*)d_out;

    const int C = in_sizes[3];              // 40
    const int F = in_sizes[2] / C;          // 64
    const int N = in_sizes[0] / F;          // 100000
    const int E = in_sizes[1] / 2;          // 1200000
    (void)F;

    const int* src = ei;
    const int* dst = ei + E;
    const int T = E + N;                    // CSR entries incl self-loops

    // ws layout, each segment 256B-aligned
    char* w8 = (char*)d_ws;
    auto alloc = [&](size_t bytes) {
        char* p = w8;
        w8 += (bytes + 255) & ~(size_t)255;
        return p;
    };
    int*   cnt     = (int*)  alloc((size_t)N * 4);
    int*   row_ptr = (int*)  alloc((size_t)(N + 1) * 4);
    int*   cursor  = (int*)  alloc((size_t)N * 4);
    int*   blkSums = (int*)  alloc(128 * 4);
    float* dinv    = (float*)alloc((size_t)N * 4);
    int*   csr_src = (int*)  alloc((size_t)T * 4);
    float* csr_w   = (float*)alloc((size_t)T * 4);
    unsigned short* p16 = (unsigned short*)alloc((size_t)N * CPAD * 2);
    unsigned int*   y16 = (unsigned int*)  alloc((size_t)N * 32 * 4);

    const int B = 256;
    const int nb = (N + 1023) / 1024;       // scan blocks (<=128)

    k_zero <<<(N + B - 1) / B, B, 0, stream>>>(cnt, N);
    k_count<<<(E + B - 1) / B, B, 0, stream>>>(dst, cnt, E);
    k_dinv <<<(N + B - 1) / B, B, 0, stream>>>(cnt, dinv, N);

    k_scan1<<<nb, B, 0, stream>>>(cnt, row_ptr, blkSums, N);
    k_scan2<<<1, 128, 0, stream>>>(blkSums, nb);
    k_scan3<<<(N + 1 + B - 1) / B, B, 0, stream>>>(row_ptr, cursor, blkSums, N, T);

    k_fill <<<(T + B - 1) / B, B, 0, stream>>>(src, dst, dinv, cursor,
                                               csr_src, csr_w, E, N);

    k_proj <<<(N + 3) / 4, B, 0, stream>>>(x, W, p16, N, C);

    k_hop1 <<<(N + 3) / 4, B, 0, stream>>>(row_ptr, csr_src, csr_w,
                                           (const unsigned int*)p16, y16, N);

    k_hop2_lsm<<<(N + 3) / 4, B, 0, stream>>>(row_ptr, csr_src, csr_w,
                                              y16, b, out, N, C);
}